// Round 1
// 149.741 us; speedup vs baseline: 1.0843x; 1.0843x over previous
//
#include <hip/hip_runtime.h>
#include <hip/hip_bf16.h>

// Problem constants
#define D       512       // embedding dim (= C)
#define K       2048      // codebook size
#define HW      1024      // 32*32
#define N_TOK   16384     // 16*HW
#define NUMEL   8388608   // 16*512*32*32

typedef __attribute__((ext_vector_type(8))) short  short8;   // 8 bf16 = 4 VGPRs
typedef __attribute__((ext_vector_type(4))) float  floatx4;

// async global->LDS DMA, 16 B per lane; LDS dest is wave-uniform base + lane*16
#define GLD_LDS16(gptr, lptr) \
    __builtin_amdgcn_global_load_lds((const __attribute__((address_space(1))) void*)(gptr), \
                                     (__attribute__((address_space(3))) void*)(lptr), 16, 0, 0)

// ---- ws layout (bytes) ----
#define WS_ZB    0           // bf16 [16384][512]
#define WS_EB    16777216    // bf16 [2048][512]
#define WS_ESQ   18874368    // f32  [2048]
#define WS_MINB  18882560    // u32  [16384] packed (21-bit dist key | 11-bit idx); init in kp
#define WS_PZ    18948096    // f32  [2048]  per-kp-block sum z^2 partials (plain writes)
#define WS_PARTS 18956288    // f32  [256]   per-strip decoded-key partials (plain writes)
#define WS_CNT2  18957312    // u32  [1]     completion counter (zeroed by kp)

// monotone fp32 -> sortable u32, and its inverse
__device__ __forceinline__ unsigned int fkey(float f) {
    unsigned int b = __float_as_uint(f);
    return b ^ ((unsigned int)((int)b >> 31) | 0x80000000u);
}
__device__ __forceinline__ float unfkey(unsigned int u) {
    unsigned int b = (u & 0x80000000u) ? (u ^ 0x80000000u) : ~u;
    return __uint_as_float(b);
}

// ---------------- Kernel P: fused prep (unchanged) ----------------
__global__ __launch_bounds__(256) void kp(const float* __restrict__ z,
                                          const float* __restrict__ emb,
                                          __hip_bfloat16* __restrict__ zb,
                                          __hip_bfloat16* __restrict__ eb,
                                          float* __restrict__ esq,
                                          float* __restrict__ pz,
                                          unsigned int* __restrict__ minb,
                                          unsigned int* __restrict__ cnt2) {
    int blk = blockIdx.x;
    int tid = threadIdx.x;
    if (blk < 2048) {
        if (tid < 8) minb[blk * 8 + tid] = 0xFFFFFFFFu;
        if (blk == 0 && tid == 8) *cnt2 = 0u;
        __shared__ float t[64][65];
        __shared__ float ls[4];
        int b  = blk >> 7;
        int dt = (blk >> 4) & 7;
        int nt = blk & 15;
        int d0 = dt * 64, n0 = nt * 64;
        const float* zp = z + ((size_t)b * D + d0) * HW + n0;
        float s = 0.f;
#pragma unroll
        for (int i = 0; i < 4; ++i) {
            int e = tid + 256 * i;
            int r = e >> 4, c4 = e & 15;
            float4 v = *(const float4*)(zp + (size_t)r * HW + c4 * 4);
            s += v.x * v.x + v.y * v.y + v.z * v.z + v.w * v.w;
            t[r][c4 * 4 + 0] = v.x; t[r][c4 * 4 + 1] = v.y;
            t[r][c4 * 4 + 2] = v.z; t[r][c4 * 4 + 3] = v.w;
        }
#pragma unroll
        for (int o = 32; o; o >>= 1) s += __shfl_down(s, o);
        if ((tid & 63) == 0) ls[tid >> 6] = s;
        __syncthreads();
        if (tid == 0) pz[blk] = ls[0] + ls[1] + ls[2] + ls[3];
        __hip_bfloat16* op = zb + ((size_t)(b * HW + n0)) * D + d0;
#pragma unroll
        for (int i = 0; i < 4; ++i) {
            int e = tid + 256 * i;
            int rn = e >> 4, cd4 = e & 15;
            __hip_bfloat16 q0 = __float2bfloat16(t[cd4 * 4 + 0][rn]);
            __hip_bfloat16 q1 = __float2bfloat16(t[cd4 * 4 + 1][rn]);
            __hip_bfloat16 q2 = __float2bfloat16(t[cd4 * 4 + 2][rn]);
            __hip_bfloat16 q3 = __float2bfloat16(t[cd4 * 4 + 3][rn]);
            ushort4 u;
            u.x = *(unsigned short*)&q0; u.y = *(unsigned short*)&q1;
            u.z = *(unsigned short*)&q2; u.w = *(unsigned short*)&q3;
            *(ushort4*)(op + (size_t)rn * D + cd4 * 4) = u;
        }
    } else {
        int k = blk - 2048;
        const float* ep = emb + (size_t)k * D;
        float s = 0.f;
        for (int d = tid; d < D; d += 256) {
            float v = ep[d];
            s += v * v;
            eb[(size_t)k * D + d] = __float2bfloat16(v);
        }
#pragma unroll
        for (int o = 32; o; o >>= 1) s += __shfl_down(s, o);
        __shared__ float ls[4];
        if ((tid & 63) == 0) ls[tid >> 6] = s;
        __syncthreads();
        if (tid == 0) esq[k] = ls[0] + ls[1] + ls[2] + ls[3];
    }
}

// ---------------- Kernel G2: 256x256 tile, 8-wave, ring-of-4 pipelined MFMA GEMM + argmin ----------------
// grid 512 blocks x 512 thr. K split into 16 subtiles of 32; 4-deep LDS ring so subtile s+3
// stages (global_load_lds) while s computes. Boundary: s_waitcnt vmcnt(8) (counted, never 0
// in steady state) + raw s_barrier. XOR swizzle (col ^ (row>>1)&3 on 4x uint4 rows) -> 2-way
// max bank aliasing (free). setprio(1) around MFMA clusters. LDS 128 KiB -> 1 block/CU.
__global__ __launch_bounds__(512, 2) void kg(const __hip_bfloat16* __restrict__ zb,
                                             const __hip_bfloat16* __restrict__ eb,
                                             const float* __restrict__ esq,
                                             unsigned int* __restrict__ minb) {
    __shared__ __hip_bfloat16 As[4][256 * 32];   // 4 ring slots, 16 KiB each
    __shared__ __hip_bfloat16 Bs[4][256 * 32];

    // bijective XCD swizzle: XCD x owns mtiles x*8..x*8+7 (A 2MB + B 2MB -> L2-fit)
    int bid   = blockIdx.x;
    int swzb  = (bid & 7) * 64 + (bid >> 3);
    int mtile = swzb >> 3;            // 0..63
    int ntile = swzb & 7;             // 0..7

    int tid  = threadIdx.x;
    int wv   = tid >> 6;              // 0..7
    int lane = tid & 63;
    int wm   = wv >> 2, wnn = wv & 3; // 2x4 wave grid, wave tile 128(M) x 64(N)
    int lrow = lane & 15, lquad = lane >> 4;
    int rl4  = lane >> 2, c4 = lane & 3;       // staging: 16 rows x 4 uint4 per wave-call
    int csw  = c4 ^ ((lane >> 3) & 3);         // pre-swizzled global col; key = (row>>1)&3
    int kR   = (lrow >> 1) & 3;                // read-side swizzle key

    const uint4* Ag = (const uint4*)(zb + (size_t)mtile * 256 * D);  // row stride 64 uint4
    const uint4* Bg = (const uint4*)(eb + (size_t)ntile * 256 * D);

    floatx4 acc[8][4];
#pragma unroll
    for (int f = 0; f < 8; ++f)
#pragma unroll
        for (int g = 0; g < 4; ++g) acc[f][g] = (floatx4){0.f, 0.f, 0.f, 0.f};

    // stage subtile ss into ring slot ss&3: 4 wave-GLDs (A lo/hi, B lo/hi), 16 rows/wave each
#define STAGE(ss) do {                                                                     \
        const int slot_ = (ss) & 3;                                                        \
        const int ko_   = (ss) * 4;                                                        \
        GLD_LDS16(Ag + (size_t)(      wv*16 + rl4) * 64 + ko_ + csw, &As[slot_][(      wv*16) * 32]); \
        GLD_LDS16(Bg + (size_t)(      wv*16 + rl4) * 64 + ko_ + csw, &Bs[slot_][(      wv*16) * 32]); \
        GLD_LDS16(Ag + (size_t)(128 + wv*16 + rl4) * 64 + ko_ + csw, &As[slot_][(128 + wv*16) * 32]); \
        GLD_LDS16(Bg + (size_t)(128 + wv*16 + rl4) * 64 + ko_ + csw, &Bs[slot_][(128 + wv*16) * 32]); \
    } while (0)

    // prologue: fill 3 ring slots; wait subtile 0 landed (1,2 stay in flight)
    STAGE(0); STAGE(1); STAGE(2);
    asm volatile("s_waitcnt vmcnt(8)" ::: "memory");
    __builtin_amdgcn_s_barrier();
    __builtin_amdgcn_sched_barrier(0);

#pragma unroll 16
    for (int s = 0; s < 16; ++s) {
        const int slot = s & 3;
        if (s + 3 < 16) STAGE(s + 3);    // slot (s-1)&3: all reads done before last barrier

        short8 bfr[4], af[4];
#pragma unroll
        for (int g = 0; g < 4; ++g)
            bfr[g] = *(const short8*)&Bs[slot][(wnn * 64 + g * 16 + lrow) * 32 + ((lquad ^ kR) << 3)];
#pragma unroll
        for (int f = 0; f < 4; ++f)
            af[f] = *(const short8*)&As[slot][(wm * 128 + f * 16 + lrow) * 32 + ((lquad ^ kR) << 3)];
        __builtin_amdgcn_s_setprio(1);
#pragma unroll
        for (int f = 0; f < 4; ++f)
#pragma unroll
            for (int g = 0; g < 4; ++g)
                acc[f][g] = __builtin_amdgcn_mfma_f32_16x16x32_bf16(af[f], bfr[g], acc[f][g], 0, 0, 0);
        __builtin_amdgcn_s_setprio(0);
#pragma unroll
        for (int f = 0; f < 4; ++f)
            af[f] = *(const short8*)&As[slot][(wm * 128 + 64 + f * 16 + lrow) * 32 + ((lquad ^ kR) << 3)];
        __builtin_amdgcn_s_setprio(1);
#pragma unroll
        for (int f = 0; f < 4; ++f)
#pragma unroll
            for (int g = 0; g < 4; ++g)
                acc[f + 4][g] = __builtin_amdgcn_mfma_f32_16x16x32_bf16(af[f], bfr[g], acc[f + 4][g], 0, 0, 0);
        __builtin_amdgcn_s_setprio(0);

        // boundary: subtile s+1 must be landed; s+2,s+3 stay in flight (8 loads)
        __builtin_amdgcn_sched_barrier(0);
        if (s < 13)       asm volatile("s_waitcnt vmcnt(8) lgkmcnt(0)" ::: "memory");
        else if (s == 13) asm volatile("s_waitcnt vmcnt(4) lgkmcnt(0)" ::: "memory");
        else if (s == 14) asm volatile("s_waitcnt vmcnt(0) lgkmcnt(0)" ::: "memory");
        if (s < 15) __builtin_amdgcn_s_barrier();
        __builtin_amdgcn_sched_barrier(0);
    }
#undef STAGE

    // ---- epilogue: dist = esq[n] - 2*dot; per-wave 16-lane argmin, LDS combine across
    // the 4 N-waves (keeps atomicMin at 1 per output row per block) ----
    float es[4];
#pragma unroll
    for (int g = 0; g < 4; ++g) es[g] = esq[ntile * 256 + wnn * 64 + g * 16 + lrow];

    unsigned int* scr = (unsigned int*)&As[0][0];   // 4*256 u32 = 4 KiB, slot 0 is dead (last subtile used slot 3)
#pragma unroll
    for (int f = 0; f < 8; ++f) {
#pragma unroll
        for (int r = 0; r < 4; ++r) {
            unsigned int best = 0xFFFFFFFFu;
#pragma unroll
            for (int g = 0; g < 4; ++g) {
                float dist = es[g] - 2.0f * acc[f][g][r];
                unsigned int kidx = (unsigned int)(ntile * 256 + wnn * 64 + g * 16 + lrow);
                unsigned int p = (fkey(dist) & 0xFFFFF800u) | kidx;
                best = p < best ? p : best;
            }
#pragma unroll
            for (int o = 1; o < 16; o <<= 1) {
                unsigned int other = (unsigned int)__shfl_xor((int)best, o);
                best = other < best ? other : best;
            }
            if (lrow == 0)
                scr[wnn * 256 + wm * 128 + f * 16 + lquad * 4 + r] = best;
        }
    }
    __syncthreads();
    if (tid < 256) {
        unsigned int b0 = scr[tid];
        unsigned int b1 = scr[256 + tid];
        unsigned int b2 = scr[512 + tid];
        unsigned int b3 = scr[768 + tid];
        b0 = b1 < b0 ? b1 : b0;
        b2 = b3 < b2 ? b3 : b2;
        b0 = b2 < b0 ? b2 : b0;
        atomicMin(&minb[mtile * 256 + tid], b0);
    }
}

// ---------------- Kernel O3: gather + NCHW write + loss (unchanged) ----------------
__global__ __launch_bounds__(256) void ko3(const float* __restrict__ emb,
                                           const unsigned int* __restrict__ minb,
                                           const float* __restrict__ pz,
                                           float* __restrict__ out,
                                           float* __restrict__ parts,
                                           unsigned int* __restrict__ cnt2) {
    __shared__ int idx[64];
    __shared__ float qt[2][64][65];
    __shared__ float red[4];
    __shared__ int finflag;
    int blk = blockIdx.x;
    int strip = blk >> 1;
    int chalf = blk & 1;
    int b = strip >> 4, hw0 = (strip & 15) * 64;
    int tid = threadIdx.x;
    unsigned int mykey = 0;
    if (tid < 64) {
        mykey = minb[strip * 64 + tid];
        idx[tid] = (int)(mykey & 0x7FFu);
    }
    if (tid == 0) finflag = 0;
    __syncthreads();

    if (chalf == 0 && tid < 64) {
        float v = unfkey(mykey & 0xFFFFF800u);
#pragma unroll
        for (int o = 32; o; o >>= 1) v += __shfl_down(v, o);
        if (tid == 0) {
            parts[strip] = v;
            __threadfence();
            finflag = (atomicAdd(cnt2, 1u) == 255u);
        }
    }

#pragma unroll
    for (int s = 0; s < 4; ++s) {
        int c0 = chalf * 256 + s * 64;
        int p = s & 1;
#pragma unroll
        for (int i = 0; i < 4; ++i) {
            int e = tid + 256 * i;
            int tr = e >> 4, c4 = e & 15;
            float4 v = *(const float4*)(emb + (size_t)idx[tr] * D + c0 + c4 * 4);
            qt[p][tr][c4 * 4 + 0] = v.x; qt[p][tr][c4 * 4 + 1] = v.y;
            qt[p][tr][c4 * 4 + 2] = v.z; qt[p][tr][c4 * 4 + 3] = v.w;
        }
        __syncthreads();
        float* op = out + ((size_t)b * D + c0) * HW + hw0;
#pragma unroll
        for (int i = 0; i < 4; ++i) {
            int e = tid + 256 * i;
            int r = e >> 4, h4 = e & 15;
            float4 q;
            q.x = qt[p][h4 * 4 + 0][r]; q.y = qt[p][h4 * 4 + 1][r];
            q.z = qt[p][h4 * 4 + 2][r]; q.w = qt[p][h4 * 4 + 3][r];
            *(float4*)(op + (size_t)r * HW + h4 * 4) = q;
        }
    }

    __syncthreads();
    if (finflag) {
        float sv = atomicAdd(&parts[tid], 0.0f);
#pragma unroll
        for (int k8 = 0; k8 < 8; ++k8) sv += pz[tid * 8 + k8];
#pragma unroll
        for (int o = 32; o; o >>= 1) sv += __shfl_down(sv, o);
        if ((tid & 63) == 0) red[tid >> 6] = sv;
        __syncthreads();
        if (tid == 0)
            out[NUMEL] = 1.25f * (red[0] + red[1] + red[2] + red[3]) / 8388608.0f;
    }
}

extern "C" void kernel_launch(void* const* d_in, const int* in_sizes, int n_in,
                              void* d_out, int out_size, void* d_ws, size_t ws_size,
                              hipStream_t stream) {
    const float* z   = (const float*)d_in[0];   // [16,512,32,32]
    const float* emb = (const float*)d_in[1];   // [2048,512]
    char* ws = (char*)d_ws;
    __hip_bfloat16* zb   = (__hip_bfloat16*)(ws + WS_ZB);
    __hip_bfloat16* eb   = (__hip_bfloat16*)(ws + WS_EB);
    float*          esq  = (float*)(ws + WS_ESQ);
    unsigned int*   minb = (unsigned int*)(ws + WS_MINB);
    float*          pz   = (float*)(ws + WS_PZ);
    float*          parts= (float*)(ws + WS_PARTS);
    unsigned int*   cnt2 = (unsigned int*)(ws + WS_CNT2);
    float* out = (float*)d_out;

    kp <<<4096, 256, 0, stream>>>(z, emb, zb, eb, esq, pz, minb, cnt2);
    kg <<< 512, 512, 0, stream>>>(zb, eb, esq, minb);
    ko3<<< 512, 256, 0, stream>>>(emb, minb, pz, out, parts, cnt2);
}